// Round 16
// baseline (480.007 us; speedup 1.0000x reference)
//
#include <hip/hip_runtime.h>
#include <math.h>

#define Sn 4
#define Bn 8
#define Ln 512
#define Dn 128
#define Hn 128
#define NOPn 64
#define Wn 2048

// ESTABLISHED: inputs fp32 insertion order; output fp32; bf16-space compare
// (thr 3.6e-2); ws >= 26MB. R13 491us -> R15 468us (agg_k2 95us @1.4TB/s,
// VALU-throttled). R16: pure-stream ww bitpack (R14's mask kernel hit
// 2.8TB/s) + scan-based gather + dual-output GEMM for wkh/wsh.

__device__ __forceinline__ float bf2f(unsigned short u) {
    return __uint_as_float(((unsigned int)u) << 16);
}
__device__ __forceinline__ unsigned short f2bf(float f) {
    unsigned int u = __float_as_uint(f);
    return (unsigned short)((u + 0x7FFFu + ((u >> 16) & 1u)) >> 16);  // RNE
}

// ---------------------------------------------------------------------------
// GEMM: C[M,128] = (relu?)(A[M,K] @ W[K,128] + b). ABF: A bf16. OBF: C bf16.
// ---------------------------------------------------------------------------
template <int K, int RELU, int OBF, int ABF>
__global__ __launch_bounds__(256) void gemm_k(const void* __restrict__ Av,
                                              const float* __restrict__ Wm,
                                              const float* __restrict__ bias,
                                              void* __restrict__ Cv) {
    __shared__ __align__(16) float lA[32][68];
    __shared__ __align__(16) float lW[32][132];
    const int tid = threadIdx.x;
    const int m0 = blockIdx.x * 64;
    float acc[4][8] = {};
    const int r0 = (tid & 15) * 4;
    const int h0 = (tid >> 4) * 8;

    for (int k0 = 0; k0 < K; k0 += 32) {
        __syncthreads();
        {
            const int r = tid >> 2, kk = (tid & 3) * 8;
            if (ABF) {
                const unsigned short* src = (const unsigned short*)Av + (size_t)(m0 + r) * K + (k0 + kk);
                alignas(16) unsigned short us[8];
                *reinterpret_cast<uint4*>(us) = *reinterpret_cast<const uint4*>(src);
#pragma unroll
                for (int j = 0; j < 8; ++j) lA[kk + j][r] = bf2f(us[j]);
            } else {
                const float* src = (const float*)Av + (size_t)(m0 + r) * K + (k0 + kk);
                float4 v0 = reinterpret_cast<const float4*>(src)[0];
                float4 v1 = reinterpret_cast<const float4*>(src)[1];
                lA[kk + 0][r] = v0.x; lA[kk + 1][r] = v0.y;
                lA[kk + 2][r] = v0.z; lA[kk + 3][r] = v0.w;
                lA[kk + 4][r] = v1.x; lA[kk + 5][r] = v1.y;
                lA[kk + 6][r] = v1.z; lA[kk + 7][r] = v1.w;
            }
        }
        {
            const int kk = tid >> 3, hh = (tid & 7) * 16;
            const float* src = Wm + (size_t)(k0 + kk) * 128 + hh;
#pragma unroll
            for (int q = 0; q < 4; ++q) {
                float4 v = reinterpret_cast<const float4*>(src)[q];
                lW[kk][hh + 4 * q + 0] = v.x;
                lW[kk][hh + 4 * q + 1] = v.y;
                lW[kk][hh + 4 * q + 2] = v.z;
                lW[kk][hh + 4 * q + 3] = v.w;
            }
        }
        __syncthreads();
#pragma unroll
        for (int k = 0; k < 32; ++k) {
            float4 a  = *reinterpret_cast<const float4*>(&lA[k][r0]);
            float4 w0 = *reinterpret_cast<const float4*>(&lW[k][h0]);
            float4 w1 = *reinterpret_cast<const float4*>(&lW[k][h0 + 4]);
            float av[4] = {a.x, a.y, a.z, a.w};
            float wv[8] = {w0.x, w0.y, w0.z, w0.w, w1.x, w1.y, w1.z, w1.w};
#pragma unroll
            for (int i = 0; i < 4; ++i)
#pragma unroll
                for (int j = 0; j < 8; ++j) acc[i][j] = fmaf(av[i], wv[j], acc[i][j]);
        }
    }
    float bv[8];
#pragma unroll
    for (int j = 0; j < 8; ++j) bv[j] = bias[h0 + j];
#pragma unroll
    for (int i = 0; i < 4; ++i) {
        float o[8];
#pragma unroll
        for (int j = 0; j < 8; ++j) {
            float v = acc[i][j] + bv[j];
            if (RELU) v = fmaxf(v, 0.f);
            o[j] = v;
        }
        if (OBF) {
            alignas(16) unsigned short us[8];
#pragma unroll
            for (int j = 0; j < 8; ++j) us[j] = f2bf(o[j]);
            unsigned short* dst = (unsigned short*)Cv + (size_t)(m0 + r0 + i) * 128 + h0;
            *reinterpret_cast<uint4*>(dst) = *reinterpret_cast<const uint4*>(us);
        } else {
            float* dst = (float*)Cv + (size_t)(m0 + r0 + i) * 128 + h0;
            *reinterpret_cast<float4*>(dst)     = reinterpret_cast<float4&>(o[0]);
            *reinterpret_cast<float4*>(dst + 4) = reinterpret_cast<float4&>(o[4]);
        }
    }
}

// ---------------------------------------------------------------------------
// Dual-output GEMM (K=128): C1 = A@W1+b1, C2 = A@W2+b2, bf16 out.
// A staged once; W1/W2 tiles both in LDS.
// ---------------------------------------------------------------------------
__global__ __launch_bounds__(256) void gemm2_k(const float* __restrict__ A,
                                               const float* __restrict__ W1,
                                               const float* __restrict__ W2,
                                               const float* __restrict__ b1,
                                               const float* __restrict__ b2,
                                               unsigned short* __restrict__ C1,
                                               unsigned short* __restrict__ C2) {
    __shared__ __align__(16) float lA[32][68];
    __shared__ __align__(16) float lW1[32][132];
    __shared__ __align__(16) float lW2[32][132];
    const int tid = threadIdx.x;
    const int m0 = blockIdx.x * 64;
    float acc1[4][8] = {}, acc2[4][8] = {};
    const int r0 = (tid & 15) * 4;
    const int h0 = (tid >> 4) * 8;

    for (int k0 = 0; k0 < 128; k0 += 32) {
        __syncthreads();
        {
            const int r = tid >> 2, kk = (tid & 3) * 8;
            const float* src = A + (size_t)(m0 + r) * 128 + (k0 + kk);
            float4 v0 = reinterpret_cast<const float4*>(src)[0];
            float4 v1 = reinterpret_cast<const float4*>(src)[1];
            lA[kk + 0][r] = v0.x; lA[kk + 1][r] = v0.y;
            lA[kk + 2][r] = v0.z; lA[kk + 3][r] = v0.w;
            lA[kk + 4][r] = v1.x; lA[kk + 5][r] = v1.y;
            lA[kk + 6][r] = v1.z; lA[kk + 7][r] = v1.w;
        }
        {
            const int kk = tid >> 3, hh = (tid & 7) * 16;
            const float* s1 = W1 + (size_t)(k0 + kk) * 128 + hh;
            const float* s2 = W2 + (size_t)(k0 + kk) * 128 + hh;
#pragma unroll
            for (int q = 0; q < 4; ++q) {
                float4 v1 = reinterpret_cast<const float4*>(s1)[q];
                float4 v2 = reinterpret_cast<const float4*>(s2)[q];
                lW1[kk][hh + 4 * q + 0] = v1.x; lW1[kk][hh + 4 * q + 1] = v1.y;
                lW1[kk][hh + 4 * q + 2] = v1.z; lW1[kk][hh + 4 * q + 3] = v1.w;
                lW2[kk][hh + 4 * q + 0] = v2.x; lW2[kk][hh + 4 * q + 1] = v2.y;
                lW2[kk][hh + 4 * q + 2] = v2.z; lW2[kk][hh + 4 * q + 3] = v2.w;
            }
        }
        __syncthreads();
#pragma unroll
        for (int k = 0; k < 32; ++k) {
            float4 a   = *reinterpret_cast<const float4*>(&lA[k][r0]);
            float4 w10 = *reinterpret_cast<const float4*>(&lW1[k][h0]);
            float4 w11 = *reinterpret_cast<const float4*>(&lW1[k][h0 + 4]);
            float4 w20 = *reinterpret_cast<const float4*>(&lW2[k][h0]);
            float4 w21 = *reinterpret_cast<const float4*>(&lW2[k][h0 + 4]);
            float av[4] = {a.x, a.y, a.z, a.w};
            float wv1[8] = {w10.x, w10.y, w10.z, w10.w, w11.x, w11.y, w11.z, w11.w};
            float wv2[8] = {w20.x, w20.y, w20.z, w20.w, w21.x, w21.y, w21.z, w21.w};
#pragma unroll
            for (int i = 0; i < 4; ++i)
#pragma unroll
                for (int j = 0; j < 8; ++j) {
                    acc1[i][j] = fmaf(av[i], wv1[j], acc1[i][j]);
                    acc2[i][j] = fmaf(av[i], wv2[j], acc2[i][j]);
                }
        }
    }
    float bv1[8], bv2[8];
#pragma unroll
    for (int j = 0; j < 8; ++j) { bv1[j] = b1[h0 + j]; bv2[j] = b2[h0 + j]; }
#pragma unroll
    for (int i = 0; i < 4; ++i) {
        alignas(16) unsigned short u1[8], u2[8];
#pragma unroll
        for (int j = 0; j < 8; ++j) {
            u1[j] = f2bf(acc1[i][j] + bv1[j]);
            u2[j] = f2bf(acc2[i][j] + bv2[j]);
        }
        const size_t off = (size_t)(m0 + r0 + i) * 128 + h0;
        *reinterpret_cast<uint4*>(C1 + off) = *reinterpret_cast<const uint4*>(u1);
        *reinterpret_cast<uint4*>(C2 + off) = *reinterpret_cast<const uint4*>(u2);
    }
}

// ---------------------------------------------------------------------------
// word_o: slot0. One wave per (b,w).
// ---------------------------------------------------------------------------
__global__ __launch_bounds__(256) void word_o_k(const float* __restrict__ wop,
                                                const unsigned short* __restrict__ oph,
                                                unsigned short* __restrict__ neigh) {
    const int gt = blockIdx.x * 256 + threadIdx.x;
    const int wave = gt >> 6, lane = threadIdx.x & 63;
    const int b = wave >> 11, w = wave & 2047;
    const float m = wop[((size_t)(b * Wn + w)) * NOPn + lane];
    unsigned long long bal = __ballot(m != 0.f);
    float a0 = 0.f, a1 = 0.f;
    const unsigned short* base = oph + (size_t)b * NOPn * Hn + 2 * lane;
    while (bal) {
        const int o = __ffsll(bal) - 1;
        bal &= bal - 1;
        ushort2 v = *reinterpret_cast<const ushort2*>(base + o * Hn);
        a0 += bf2f(v.x);
        a1 += bf2f(v.y);
    }
    float ss = a0 * a0 + a1 * a1;
#pragma unroll
    for (int off = 1; off < 64; off <<= 1) ss += __shfl_xor(ss, off);
    const float sc = 1.f / (sqrtf(ss) + 1e-30f);
    ushort2 o2 = {f2bf(a0 * sc), f2bf(a1 * sc)};
    *reinterpret_cast<ushort2*>(neigh + ((size_t)(b * Wn + w)) * 384 + 2 * lane) = o2;
}

// ---------------------------------------------------------------------------
// pack_bits: bit[e] = (src[e]!=0), ballot-packed. Chunk c = 256 elems;
// word c*4+j bit L <-> elem c*256+L*4+j. 2-chunk unroll, loads hoisted
// ahead of ballots (R14's mask kernel rate: ~2.8TB/s effective).
// ---------------------------------------------------------------------------
__global__ __launch_bounds__(256) void pack_bits(const float* __restrict__ src,
                                                 unsigned long long* __restrict__ mk,
                                                 int nchunk) {
    const int lane = threadIdx.x & 63;
    const int wave0 = (blockIdx.x * 256 + threadIdx.x) >> 6;
    const int nwave = (gridDim.x * 256) >> 6;
    for (int c = wave0 * 2; c < nchunk; c += nwave * 2) {
        const float4 va = *reinterpret_cast<const float4*>(src + (size_t)c * 256 + lane * 4);
        const float4 vb = *reinterpret_cast<const float4*>(src + (size_t)(c + 1) * 256 + lane * 4);
        unsigned long long a0 = __ballot(va.x != 0.f);
        unsigned long long a1 = __ballot(va.y != 0.f);
        unsigned long long a2 = __ballot(va.z != 0.f);
        unsigned long long a3 = __ballot(va.w != 0.f);
        unsigned long long b0 = __ballot(vb.x != 0.f);
        unsigned long long b1 = __ballot(vb.y != 0.f);
        unsigned long long b2 = __ballot(vb.z != 0.f);
        unsigned long long b3 = __ballot(vb.w != 0.f);
        if (lane == 0) {
            ulonglong2 wa0 = {a0, a1}, wa1 = {a2, a3};
            ulonglong2 wb0 = {b0, b1}, wb1 = {b2, b3};
            *reinterpret_cast<ulonglong2*>(mk + (size_t)c * 4)     = wa0;
            *reinterpret_cast<ulonglong2*>(mk + (size_t)c * 4 + 2) = wa1;
            *reinterpret_cast<ulonglong2*>(mk + (size_t)(c + 1) * 4)     = wb0;
            *reinterpret_cast<ulonglong2*>(mk + (size_t)(c + 1) * 4 + 2) = wb1;
        }
    }
}

// ---------------------------------------------------------------------------
// gather_k3: slot1. One block (4 waves) per row.
//   ph1 (wave 0): read 32 u64 bitmask words, popcount-prefix-scan, expand
//                 hit indices into LDS.
//   ph2: lane-parallel wem probe at hits.
//   ph3: 4 waves split hits, gather wkh rows.
//   ph4: reduce + l2 + store.
// ---------------------------------------------------------------------------
__global__ __launch_bounds__(256) void gather_k3(const unsigned long long* __restrict__ mk,
                                                 const float* __restrict__ wem,
                                                 const unsigned short* __restrict__ wkh,
                                                 unsigned short* __restrict__ neigh) {
    const int row = blockIdx.x;  // b*2048 + v
    const int b = row >> 11;
    const int t = threadIdx.x;
    const int lane = t & 63, wv = t >> 6;
    __shared__ int idxs[512];
    __shared__ int keep[512];
    __shared__ int cntS;
    __shared__ float part[4][128];
    if (wv == 0) {
        unsigned long long w = 0ull;
        int pc = 0;
        if (lane < 32) {
            w = mk[(size_t)row * 32 + lane];
            pc = __popcll(w);
        }
        int pre = pc;
#pragma unroll
        for (int off = 1; off < 32; off <<= 1) {
            int v = __shfl_up(pre, off);
            if (lane >= off) pre += v;
        }
        if (lane == 31) cntS = pre;
        int pos = pre - pc;  // exclusive prefix
        const int c = lane >> 2, j = lane & 3;
        while (w) {
            const int L = __ffsll(w) - 1;
            w &= w - 1;
            if (pos < 512) idxs[pos] = c * 256 + L * 4 + j;
            ++pos;
        }
    }
    __syncthreads();
    const int n = cntS < 512 ? cntS : 512;
    for (int p = t; p < n; p += 256)
        keep[p] = (wem[(size_t)row * 2048 + idxs[p]] != 0.f) ? 1 : 0;
    __syncthreads();
    float a0 = 0.f, a1 = 0.f;
    for (int p = wv; p < n; p += 4) {
        if (keep[p]) {
            const int w = idxs[p];
            const int s = w >> 9, l = w & 511;
            ushort2 x = *reinterpret_cast<const ushort2*>(
                wkh + ((size_t)((s * Bn + b) * Ln + l)) * Hn + 2 * lane);
            a0 += bf2f(x.x);
            a1 += bf2f(x.y);
        }
    }
    part[wv][2 * lane]     = a0;
    part[wv][2 * lane + 1] = a1;
    __syncthreads();
    if (wv == 0) {
        float s0 = 0.f, s1 = 0.f;
#pragma unroll
        for (int q = 0; q < 4; ++q) {
            s0 += part[q][2 * lane];
            s1 += part[q][2 * lane + 1];
        }
        float ss = s0 * s0 + s1 * s1;
#pragma unroll
        for (int off = 1; off < 64; off <<= 1) ss += __shfl_xor(ss, off);
        const float sc = 1.f / (sqrtf(ss) + 1e-30f);
        ushort2 o2 = {f2bf(s0 * sc), f2bf(s1 * sc)};
        *reinterpret_cast<ushort2*>(neigh + (size_t)row * 384 + 128 + 2 * lane) = o2;
    }
}

// ---------------------------------------------------------------------------
// agg_k2 (R15 fallback, used if ws too small for bitmask buffer).
// ---------------------------------------------------------------------------
__global__ __launch_bounds__(256) void agg_k2(const float* __restrict__ ww,
                                              const float* __restrict__ wem,
                                              const unsigned short* __restrict__ wkh,
                                              unsigned short* __restrict__ neigh) {
    const int row = blockIdx.x;
    const int b = row >> 11;
    const int t = threadIdx.x;
    const int lane = t & 63, wv = t >> 6;
    __shared__ int idxs[256];
    __shared__ int keep[256];
    __shared__ int cnt;
    __shared__ float part[4][128];
    if (t == 0) cnt = 0;
    __syncthreads();
    const float* wr = ww + (size_t)row * 2048;
#pragma unroll
    for (int q = 0; q < 2; ++q) {
        const int e0 = q * 1024 + t * 4;
        float4 v = *reinterpret_cast<const float4*>(wr + e0);
        float vv[4] = {v.x, v.y, v.z, v.w};
#pragma unroll
        for (int j = 0; j < 4; ++j) {
            if (vv[j] != 0.f) {
                int p = atomicAdd(&cnt, 1);
                if (p < 256) idxs[p] = e0 + j;
            }
        }
    }
    __syncthreads();
    const int n = cnt < 256 ? cnt : 256;
    if (t < n) keep[t] = (wem[(size_t)row * 2048 + idxs[t]] != 0.f) ? 1 : 0;
    __syncthreads();
    float a0 = 0.f, a1 = 0.f;
    for (int p = wv; p < n; p += 4) {
        if (keep[p]) {
            const int w = idxs[p];
            const int s = w >> 9, l = w & 511;
            ushort2 x = *reinterpret_cast<const ushort2*>(
                wkh + ((size_t)((s * Bn + b) * Ln + l)) * Hn + 2 * lane);
            a0 += bf2f(x.x);
            a1 += bf2f(x.y);
        }
    }
    part[wv][2 * lane]     = a0;
    part[wv][2 * lane + 1] = a1;
    __syncthreads();
    if (wv == 0) {
        float s0 = 0.f, s1 = 0.f;
#pragma unroll
        for (int q = 0; q < 4; ++q) {
            s0 += part[q][2 * lane];
            s1 += part[q][2 * lane + 1];
        }
        float ss = s0 * s0 + s1 * s1;
#pragma unroll
        for (int off = 1; off < 64; off <<= 1) ss += __shfl_xor(ss, off);
        const float sc = 1.f / (sqrtf(ss) + 1e-30f);
        ushort2 o2 = {f2bf(s0 * sc), f2bf(s1 * sc)};
        *reinterpret_cast<ushort2*>(neigh + (size_t)row * 384 + 128 + 2 * lane) = o2;
    }
}

// ---------------------------------------------------------------------------
// agg_s: slot2, fused. One wave per (s,b,i).
// ---------------------------------------------------------------------------
__global__ __launch_bounds__(256) void agg_s_k(const float* __restrict__ dep,
                                               const unsigned short* __restrict__ wsh,
                                               unsigned short* __restrict__ neigh) {
    const int gt = blockIdx.x * 256 + threadIdx.x;
    const int wave = gt >> 6, lane = threadIdx.x & 63;
    const int idx = wave;
    const int i = idx & 511;
    const int sb = idx >> 9;
    const int b = sb & 7, s = sb >> 3;
    const float* dr = dep + (size_t)idx * Ln;
    const unsigned short* base = wsh + (size_t)(sb * Ln) * Hn + 2 * lane;
    float a0 = 0.f, a1 = 0.f;
    for (int w0 = 0; w0 < Ln; w0 += 256) {
        float4 dd = *reinterpret_cast<const float4*>(dr + w0 + lane * 4);
        float dv[4] = {dd.x, dd.y, dd.z, dd.w};
#pragma unroll
        for (int j = 0; j < 4; ++j) {
            unsigned long long bal = __ballot(dv[j] != 0.f);
            while (bal) {
                const int Lb = __ffsll(bal) - 1;
                bal &= bal - 1;
                ushort2 x = *reinterpret_cast<const ushort2*>(base + (size_t)(w0 + Lb * 4 + j) * Hn);
                a0 += bf2f(x.x);
                a1 += bf2f(x.y);
            }
        }
    }
    float ss = a0 * a0 + a1 * a1;
#pragma unroll
    for (int off = 1; off < 64; off <<= 1) ss += __shfl_xor(ss, off);
    const float sc = 1.f / (sqrtf(ss) + 1e-30f);
    const int w = s * Ln + i;
    ushort2 o2 = {f2bf(a0 * sc), f2bf(a1 * sc)};
    *reinterpret_cast<ushort2*>(neigh + ((size_t)(b * Wn + w)) * 384 + 256 + 2 * lane) = o2;
}

// ---------------------------------------------------------------------------
// final2: 1024 thr/block, slice-parallel pooling + LDS-reduced GEMVs.
// ---------------------------------------------------------------------------
__global__ __launch_bounds__(1024) void final2_k(const float* __restrict__ goal,
                                                 const float* __restrict__ wes,
                                                 const float* __restrict__ wu,
                                                 const float* __restrict__ nh,
                                                 const float* __restrict__ wgW,
                                                 const float* __restrict__ wgb,
                                                 const float* __restrict__ fgW,
                                                 const float* __restrict__ fgb,
                                                 float* __restrict__ out) {
    const int b = blockIdx.x, t = threadIdx.x;
    const int d = t & 127, sl = t >> 7;
    __shared__ int idxs[Wn];
    __shared__ int cnt;
    __shared__ float red[1024];
    __shared__ float gw[Dn], nhs[Dn];
    if (t == 0) cnt = 0;
    __syncthreads();
#pragma unroll
    for (int j = 0; j < 2; ++j) {
        const int w = t * 2 + j;
        if (goal[b * Wn + w] != 0.f && wes[b * Wn + w] != 0.f) {
            const int p = atomicAdd(&cnt, 1);
            idxs[p] = w;
        }
    }
    __syncthreads();
    const int n = cnt;
    float acc = 0.f;
    for (int p = sl; p < n; p += 8) acc += wu[((size_t)b * Wn + idxs[p]) * Dn + d];
    red[t] = acc;
    __syncthreads();
    for (int s = 512; s >= 128; s >>= 1) {
        if (t < s) red[t] += red[t + s];
        __syncthreads();
    }
    if (t < 128) {
        gw[t] = red[t] / ((float)n + 1e-30f);
        nhs[t] = nh[b * Dn + t];
    }
    __syncthreads();
    float pg = 0.f;
    for (int k = sl * 16; k < sl * 16 + 16; ++k) pg = fmaf(gw[k], wgW[k * Dn + d], pg);
    red[t] = pg;
    __syncthreads();
    for (int s = 512; s >= 128; s >>= 1) {
        if (t < s) red[t] += red[t + s];
        __syncthreads();
    }
    float gu = 0.f;
    if (t < 128) gu = fmaxf(red[t] + wgb[t], 0.f);
    __syncthreads();
    float pf = 0.f;
    for (int kk = sl * 32; kk < sl * 32 + 32; ++kk) {
        const float x = (kk < 128) ? gw[kk] : nhs[kk - 128];
        pf = fmaf(x, fgW[(size_t)kk * Dn + d], pf);
    }
    red[t] = pf;
    __syncthreads();
    for (int s = 512; s >= 128; s >>= 1) {
        if (t < s) red[t] += red[t + s];
        __syncthreads();
    }
    if (t < 128) {
        const float fg = red[t] + fgb[t];
        const float forget = 1.f / (1.f + expf(-fg));
        out[b * Dn + t] = fmaxf(forget, 0.1f) * nhs[t] + (1.f - forget) * gu;
    }
}

// ---------------------------------------------------------------------------
extern "C" void kernel_launch(void* const* d_in, const int* in_sizes, int n_in,
                              void* d_out, int out_size, void* d_ws, size_t ws_size,
                              hipStream_t stream) {
    (void)in_sizes; (void)n_in; (void)out_size;
    const float* word_outputs        = (const float*)d_in[0];
    const float* node_hidden         = (const float*)d_in[1];
    const float* op_embedding        = (const float*)d_in[2];
    const float* word_operator       = (const float*)d_in[3];
    const float* word_word           = (const float*)d_in[4];
    const float* depend_relation     = (const float*)d_in[5];
    const float* word_exist_matrix   = (const float*)d_in[6];
    const float* word_exist_sequence = (const float*)d_in[7];
    const float* goal_word           = (const float*)d_in[8];
    const float* o_w_W = (const float*)d_in[9];
    const float* o_w_b = (const float*)d_in[10];
    const float* wk_W  = (const float*)d_in[11];
    const float* wk_b  = (const float*)d_in[12];
    const float* ws_W  = (const float*)d_in[13];
    const float* ws_b  = (const float*)d_in[14];
    const float* up_W  = (const float*)d_in[15];
    const float* up_b  = (const float*)d_in[16];
    const float* wg_W  = (const float*)d_in[17];
    const float* wg_b  = (const float*)d_in[18];
    const float* fg_W  = (const float*)d_in[19];
    const float* fg_b  = (const float*)d_in[20];
    float* out = (float*)d_out;

    char* ws = (char*)d_ws;
    unsigned short* oph = (unsigned short*)(ws + 0);          // 128 KB
    unsigned short* wkh = (unsigned short*)(ws + (1u << 20)); // 4 MB
    unsigned short* wsh = (unsigned short*)(ws + (5u << 20)); // 4 MB
    unsigned short* nb  = (unsigned short*)(ws + (9u << 20)); // 12 MB
    float* wu           = (float*)(ws + (1u << 20));          // 8 MB over wkh+wsh
    unsigned long long* mkw = (unsigned long long*)(ws + (21u << 20)); // 4 MB
    const bool split_ok = ws_size >= (size_t)25 * 1024 * 1024;

    gemm_k<128, 0, 1, 0><<<dim3(8), 256, 0, stream>>>(op_embedding, o_w_W, o_w_b, oph);
    gemm2_k<<<dim3(256), 256, 0, stream>>>(word_outputs, wk_W, ws_W, wk_b, ws_b, wkh, wsh);
    word_o_k<<<4096, 256, 0, stream>>>(word_operator, oph, nb);
    if (split_ok) {
        pack_bits<<<4096, 256, 0, stream>>>(word_word, mkw, 131072);
        gather_k3<<<16384, 256, 0, stream>>>(mkw, word_exist_matrix, wkh, nb);
    } else {
        agg_k2<<<16384, 256, 0, stream>>>(word_word, word_exist_matrix, wkh, nb);
    }
    agg_s_k<<<4096, 256, 0, stream>>>(depend_relation, wsh, nb);
    gemm_k<384, 1, 0, 1><<<dim3(256), 256, 0, stream>>>(nb, up_W, up_b, wu);
    final2_k<<<8, 1024, 0, stream>>>(goal_word, word_exist_sequence, wu, node_hidden,
                                     wg_W, wg_b, fg_W, fg_b, out);
}

// Round 18
// 381.034 us; speedup vs baseline: 1.2597x; 1.2597x over previous
//
#include <hip/hip_runtime.h>
#include <math.h>

#define Sn 4
#define Bn 8
#define Ln 512
#define Dn 128
#define Hn 128
#define NOPn 64
#define Wn 2048

// ESTABLISHED: inputs fp32 insertion order; output fp32; bf16-space compare
// (thr 3.6e-2); ws = 512MB. R16 key insight: only pooled rows (goal&wes,
// ~369/batch) feed the output — restrict agg+up to compacted destinations.
// (R17 resubmission — prior round hit GPUAcquisitionTimeout, never ran.)

__device__ __forceinline__ float bf2f(unsigned short u) {
    return __uint_as_float(((unsigned int)u) << 16);
}
__device__ __forceinline__ unsigned short f2bf(float f) {
    unsigned int u = __float_as_uint(f);
    return (unsigned short)((u + 0x7FFFu + ((u >> 16) & 1u)) >> 16);  // RNE
}

// ---------------------------------------------------------------------------
// GEMM (K=128, fp32 A/W, bf16 out) — used for oph.
// ---------------------------------------------------------------------------
__global__ __launch_bounds__(256) void gemm_small(const float* __restrict__ A,
                                                  const float* __restrict__ Wm,
                                                  const float* __restrict__ bias,
                                                  unsigned short* __restrict__ C) {
    __shared__ __align__(16) float lA[32][68];
    __shared__ __align__(16) float lW[32][132];
    const int tid = threadIdx.x;
    const int m0 = blockIdx.x * 64;
    float acc[4][8] = {};
    const int r0 = (tid & 15) * 4;
    const int h0 = (tid >> 4) * 8;
    for (int k0 = 0; k0 < 128; k0 += 32) {
        __syncthreads();
        {
            const int r = tid >> 2, kk = (tid & 3) * 8;
            const float* src = A + (size_t)(m0 + r) * 128 + (k0 + kk);
            float4 v0 = reinterpret_cast<const float4*>(src)[0];
            float4 v1 = reinterpret_cast<const float4*>(src)[1];
            lA[kk + 0][r] = v0.x; lA[kk + 1][r] = v0.y;
            lA[kk + 2][r] = v0.z; lA[kk + 3][r] = v0.w;
            lA[kk + 4][r] = v1.x; lA[kk + 5][r] = v1.y;
            lA[kk + 6][r] = v1.z; lA[kk + 7][r] = v1.w;
        }
        {
            const int kk = tid >> 3, hh = (tid & 7) * 16;
            const float* src = Wm + (size_t)(k0 + kk) * 128 + hh;
#pragma unroll
            for (int q = 0; q < 4; ++q) {
                float4 v = reinterpret_cast<const float4*>(src)[q];
                lW[kk][hh + 4 * q + 0] = v.x; lW[kk][hh + 4 * q + 1] = v.y;
                lW[kk][hh + 4 * q + 2] = v.z; lW[kk][hh + 4 * q + 3] = v.w;
            }
        }
        __syncthreads();
#pragma unroll
        for (int k = 0; k < 32; ++k) {
            float4 a  = *reinterpret_cast<const float4*>(&lA[k][r0]);
            float4 w0 = *reinterpret_cast<const float4*>(&lW[k][h0]);
            float4 w1 = *reinterpret_cast<const float4*>(&lW[k][h0 + 4]);
            float av[4] = {a.x, a.y, a.z, a.w};
            float wv[8] = {w0.x, w0.y, w0.z, w0.w, w1.x, w1.y, w1.z, w1.w};
#pragma unroll
            for (int i = 0; i < 4; ++i)
#pragma unroll
                for (int j = 0; j < 8; ++j) acc[i][j] = fmaf(av[i], wv[j], acc[i][j]);
        }
    }
#pragma unroll
    for (int i = 0; i < 4; ++i) {
        alignas(16) unsigned short us[8];
#pragma unroll
        for (int j = 0; j < 8; ++j) us[j] = f2bf(acc[i][j] + bias[h0 + j]);
        *reinterpret_cast<uint4*>(C + (size_t)(m0 + r0 + i) * 128 + h0) =
            *reinterpret_cast<const uint4*>(us);
    }
}

// ---------------------------------------------------------------------------
// Dual-output GEMM (K=128): wkh/wsh from word_outputs (A staged once).
// ---------------------------------------------------------------------------
__global__ __launch_bounds__(256) void gemm2_k(const float* __restrict__ A,
                                               const float* __restrict__ W1,
                                               const float* __restrict__ W2,
                                               const float* __restrict__ b1,
                                               const float* __restrict__ b2,
                                               unsigned short* __restrict__ C1,
                                               unsigned short* __restrict__ C2) {
    __shared__ __align__(16) float lA[32][68];
    __shared__ __align__(16) float lW1[32][132];
    __shared__ __align__(16) float lW2[32][132];
    const int tid = threadIdx.x;
    const int m0 = blockIdx.x * 64;
    float acc1[4][8] = {}, acc2[4][8] = {};
    const int r0 = (tid & 15) * 4;
    const int h0 = (tid >> 4) * 8;
    for (int k0 = 0; k0 < 128; k0 += 32) {
        __syncthreads();
        {
            const int r = tid >> 2, kk = (tid & 3) * 8;
            const float* src = A + (size_t)(m0 + r) * 128 + (k0 + kk);
            float4 v0 = reinterpret_cast<const float4*>(src)[0];
            float4 v1 = reinterpret_cast<const float4*>(src)[1];
            lA[kk + 0][r] = v0.x; lA[kk + 1][r] = v0.y;
            lA[kk + 2][r] = v0.z; lA[kk + 3][r] = v0.w;
            lA[kk + 4][r] = v1.x; lA[kk + 5][r] = v1.y;
            lA[kk + 6][r] = v1.z; lA[kk + 7][r] = v1.w;
        }
        {
            const int kk = tid >> 3, hh = (tid & 7) * 16;
            const float* s1 = W1 + (size_t)(k0 + kk) * 128 + hh;
            const float* s2 = W2 + (size_t)(k0 + kk) * 128 + hh;
#pragma unroll
            for (int q = 0; q < 4; ++q) {
                float4 v1 = reinterpret_cast<const float4*>(s1)[q];
                float4 v2 = reinterpret_cast<const float4*>(s2)[q];
                lW1[kk][hh + 4 * q + 0] = v1.x; lW1[kk][hh + 4 * q + 1] = v1.y;
                lW1[kk][hh + 4 * q + 2] = v1.z; lW1[kk][hh + 4 * q + 3] = v1.w;
                lW2[kk][hh + 4 * q + 0] = v2.x; lW2[kk][hh + 4 * q + 1] = v2.y;
                lW2[kk][hh + 4 * q + 2] = v2.z; lW2[kk][hh + 4 * q + 3] = v2.w;
            }
        }
        __syncthreads();
#pragma unroll
        for (int k = 0; k < 32; ++k) {
            float4 a   = *reinterpret_cast<const float4*>(&lA[k][r0]);
            float4 w10 = *reinterpret_cast<const float4*>(&lW1[k][h0]);
            float4 w11 = *reinterpret_cast<const float4*>(&lW1[k][h0 + 4]);
            float4 w20 = *reinterpret_cast<const float4*>(&lW2[k][h0]);
            float4 w21 = *reinterpret_cast<const float4*>(&lW2[k][h0 + 4]);
            float av[4] = {a.x, a.y, a.z, a.w};
            float wv1[8] = {w10.x, w10.y, w10.z, w10.w, w11.x, w11.y, w11.z, w11.w};
            float wv2[8] = {w20.x, w20.y, w20.z, w20.w, w21.x, w21.y, w21.z, w21.w};
#pragma unroll
            for (int i = 0; i < 4; ++i)
#pragma unroll
                for (int j = 0; j < 8; ++j) {
                    acc1[i][j] = fmaf(av[i], wv1[j], acc1[i][j]);
                    acc2[i][j] = fmaf(av[i], wv2[j], acc2[i][j]);
                }
        }
    }
#pragma unroll
    for (int i = 0; i < 4; ++i) {
        alignas(16) unsigned short u1[8], u2[8];
#pragma unroll
        for (int j = 0; j < 8; ++j) {
            u1[j] = f2bf(acc1[i][j] + b1[h0 + j]);
            u2[j] = f2bf(acc2[i][j] + b2[h0 + j]);
        }
        const size_t off = (size_t)(m0 + r0 + i) * 128 + h0;
        *reinterpret_cast<uint4*>(C1 + off) = *reinterpret_cast<const uint4*>(u1);
        *reinterpret_cast<uint4*>(C2 + off) = *reinterpret_cast<const uint4*>(u2);
    }
}

// ---------------------------------------------------------------------------
// compact: per-b list of pooled word indices (goal&wes nonzero). cap 1024.
// ---------------------------------------------------------------------------
__global__ __launch_bounds__(256) void compact_k(const float* __restrict__ goal,
                                                 const float* __restrict__ wes,
                                                 int* __restrict__ widx,
                                                 int* __restrict__ wcnt) {
    const int b = blockIdx.x, t = threadIdx.x;
    __shared__ int cnt;
    if (t == 0) cnt = 0;
    __syncthreads();
#pragma unroll
    for (int j = 0; j < 8; ++j) {
        const int w = t * 8 + j;
        if (goal[b * Wn + w] != 0.f && wes[b * Wn + w] != 0.f) {
            const int p = atomicAdd(&cnt, 1);
            if (p < 1024) widx[b * 1024 + p] = w;
        }
    }
    __syncthreads();
    if (t == 0) wcnt[b] = cnt < 1024 ? cnt : 1024;
}

// ---------------------------------------------------------------------------
// mega_agg: ONE block (256 thr / 4 waves) per pooled destination row.
// Computes all 3 neighbor slots into compacted nbc[p][384].
// ---------------------------------------------------------------------------
__global__ __launch_bounds__(256) void mega_agg(const int* __restrict__ widx,
                                                const int* __restrict__ wcnt,
                                                const float* __restrict__ ww,
                                                const float* __restrict__ wem,
                                                const float* __restrict__ dep,
                                                const float* __restrict__ wop,
                                                const unsigned short* __restrict__ oph,
                                                const unsigned short* __restrict__ wkh,
                                                const unsigned short* __restrict__ wsh,
                                                unsigned short* __restrict__ nbc) {
    const int slot = blockIdx.x;          // b*1024 + i
    const int b = slot >> 10, i = slot & 1023;
    if (i >= wcnt[b]) return;             // uniform exit
    const int w_dst = widx[slot];
    const int t = threadIdx.x;
    const int lane = t & 63, wv = t >> 6;

    __shared__ int kidx[512];
    __shared__ int keep[512];
    __shared__ int sidx[256];
    __shared__ int kn, sn;
    __shared__ float part1[4][128];
    __shared__ float part2[4][128];
    if (t == 0) { kn = 0; sn = 0; }
    __syncthreads();

    // --- p1: stream ww row (2048 f), dep row (512 f), wop row (64 f) ---
    const float* wwr = ww + ((size_t)(b * Wn + w_dst)) * Wn;
#pragma unroll
    for (int q = 0; q < 2; ++q) {
        const int e0 = q * 1024 + t * 4;
        float4 v = *reinterpret_cast<const float4*>(wwr + e0);
        float vv[4] = {v.x, v.y, v.z, v.w};
#pragma unroll
        for (int j = 0; j < 4; ++j)
            if (vv[j] != 0.f) {
                int p = atomicAdd(&kn, 1);
                if (p < 512) kidx[p] = e0 + j;
            }
    }
    const int sD = w_dst >> 9, lD = w_dst & 511;
    if (t < 128) {
        const float* dr = dep + ((size_t)((sD * Bn + b) * Ln + lD)) * Ln + t * 4;
        float4 v = *reinterpret_cast<const float4*>(dr);
        float vv[4] = {v.x, v.y, v.z, v.w};
#pragma unroll
        for (int j = 0; j < 4; ++j)
            if (vv[j] != 0.f) {
                int p = atomicAdd(&sn, 1);
                if (p < 256) sidx[p] = t * 4 + j;
            }
    }
    float m_op = 0.f;
    if (wv == 3) m_op = wop[((size_t)(b * Wn + w_dst)) * NOPn + lane];
    __syncthreads();

    // --- p2: wem probe at ww hits ---
    const int nk = kn < 512 ? kn : 512;
    const int ns = sn < 256 ? sn : 256;
    for (int p = t; p < nk; p += 256)
        keep[p] = (wem[((size_t)(b * Wn + w_dst)) * Wn + kidx[p]] != 0.f) ? 1 : 0;
    __syncthreads();

    // --- p3: gathers ---
    {   // slot1: wkh rows at kept ww hits (4-wave split)
        float a0 = 0.f, a1 = 0.f;
        for (int p = wv; p < nk; p += 4)
            if (keep[p]) {
                const int w = kidx[p];
                const int s = w >> 9, l = w & 511;
                ushort2 x = *reinterpret_cast<const ushort2*>(
                    wkh + ((size_t)((s * Bn + b) * Ln + l)) * Hn + 2 * lane);
                a0 += bf2f(x.x);
                a1 += bf2f(x.y);
            }
        part1[wv][2 * lane]     = a0;
        part1[wv][2 * lane + 1] = a1;
    }
    {   // slot2: wsh segment rows at dep hits (4-wave split)
        const unsigned short* base = wsh + (size_t)((sD * Bn + b) * Ln) * Hn + 2 * lane;
        float a0 = 0.f, a1 = 0.f;
        for (int p = wv; p < ns; p += 4) {
            ushort2 x = *reinterpret_cast<const ushort2*>(base + (size_t)sidx[p] * Hn);
            a0 += bf2f(x.x);
            a1 += bf2f(x.y);
        }
        part2[wv][2 * lane]     = a0;
        part2[wv][2 * lane + 1] = a1;
    }
    if (wv == 3) {  // slot0: oph rows at wop hits (wave 3 alone)
        unsigned long long bal = __ballot(m_op != 0.f);
        float a0 = 0.f, a1 = 0.f;
        const unsigned short* base = oph + (size_t)b * NOPn * Hn + 2 * lane;
        while (bal) {
            const int o = __ffsll(bal) - 1;
            bal &= bal - 1;
            ushort2 v = *reinterpret_cast<const ushort2*>(base + o * Hn);
            a0 += bf2f(v.x);
            a1 += bf2f(v.y);
        }
        float ss = a0 * a0 + a1 * a1;
#pragma unroll
        for (int off = 1; off < 64; off <<= 1) ss += __shfl_xor(ss, off);
        const float sc = 1.f / (sqrtf(ss) + 1e-30f);
        ushort2 o2 = {f2bf(a0 * sc), f2bf(a1 * sc)};
        *reinterpret_cast<ushort2*>(nbc + (size_t)slot * 384 + 2 * lane) = o2;
    }
    __syncthreads();

    // --- p4: parallel reduces (wave0 -> slot1, wave1 -> slot2) ---
    if (wv == 0) {
        float s0 = 0.f, s1 = 0.f;
#pragma unroll
        for (int q = 0; q < 4; ++q) {
            s0 += part1[q][2 * lane];
            s1 += part1[q][2 * lane + 1];
        }
        float ss = s0 * s0 + s1 * s1;
#pragma unroll
        for (int off = 1; off < 64; off <<= 1) ss += __shfl_xor(ss, off);
        const float sc = 1.f / (sqrtf(ss) + 1e-30f);
        ushort2 o2 = {f2bf(s0 * sc), f2bf(s1 * sc)};
        *reinterpret_cast<ushort2*>(nbc + (size_t)slot * 384 + 128 + 2 * lane) = o2;
    } else if (wv == 1) {
        float s0 = 0.f, s1 = 0.f;
#pragma unroll
        for (int q = 0; q < 4; ++q) {
            s0 += part2[q][2 * lane];
            s1 += part2[q][2 * lane + 1];
        }
        float ss = s0 * s0 + s1 * s1;
#pragma unroll
        for (int off = 1; off < 64; off <<= 1) ss += __shfl_xor(ss, off);
        const float sc = 1.f / (sqrtf(ss) + 1e-30f);
        ushort2 o2 = {f2bf(s0 * sc), f2bf(s1 * sc)};
        *reinterpret_cast<ushort2*>(nbc + (size_t)slot * 384 + 256 + 2 * lane) = o2;
    }
}

// ---------------------------------------------------------------------------
// up-GEMM over compacted rows (K=384, bf16 A, relu, fp32 out, cnt guard).
// ---------------------------------------------------------------------------
__global__ __launch_bounds__(256) void up_gemm_c(const unsigned short* __restrict__ A,
                                                 const float* __restrict__ Wm,
                                                 const float* __restrict__ bias,
                                                 const int* __restrict__ wcnt,
                                                 float* __restrict__ C) {
    const int m0 = blockIdx.x * 64;
    if ((m0 & 1023) >= wcnt[m0 >> 10]) return;  // whole 64-row tile unused
    __shared__ __align__(16) float lA[32][68];
    __shared__ __align__(16) float lW[32][132];
    const int tid = threadIdx.x;
    float acc[4][8] = {};
    const int r0 = (tid & 15) * 4;
    const int h0 = (tid >> 4) * 8;
    for (int k0 = 0; k0 < 384; k0 += 32) {
        __syncthreads();
        {
            const int r = tid >> 2, kk = (tid & 3) * 8;
            const unsigned short* src = A + (size_t)(m0 + r) * 384 + (k0 + kk);
            alignas(16) unsigned short us[8];
            *reinterpret_cast<uint4*>(us) = *reinterpret_cast<const uint4*>(src);
#pragma unroll
            for (int j = 0; j < 8; ++j) lA[kk + j][r] = bf2f(us[j]);
        }
        {
            const int kk = tid >> 3, hh = (tid & 7) * 16;
            const float* src = Wm + (size_t)(k0 + kk) * 128 + hh;
#pragma unroll
            for (int q = 0; q < 4; ++q) {
                float4 v = reinterpret_cast<const float4*>(src)[q];
                lW[kk][hh + 4 * q + 0] = v.x; lW[kk][hh + 4 * q + 1] = v.y;
                lW[kk][hh + 4 * q + 2] = v.z; lW[kk][hh + 4 * q + 3] = v.w;
            }
        }
        __syncthreads();
#pragma unroll
        for (int k = 0; k < 32; ++k) {
            float4 a  = *reinterpret_cast<const float4*>(&lA[k][r0]);
            float4 w0 = *reinterpret_cast<const float4*>(&lW[k][h0]);
            float4 w1 = *reinterpret_cast<const float4*>(&lW[k][h0 + 4]);
            float av[4] = {a.x, a.y, a.z, a.w};
            float wv[8] = {w0.x, w0.y, w0.z, w0.w, w1.x, w1.y, w1.z, w1.w};
#pragma unroll
            for (int i = 0; i < 4; ++i)
#pragma unroll
                for (int j = 0; j < 8; ++j) acc[i][j] = fmaf(av[i], wv[j], acc[i][j]);
        }
    }
#pragma unroll
    for (int i = 0; i < 4; ++i) {
        float o[8];
#pragma unroll
        for (int j = 0; j < 8; ++j) o[j] = fmaxf(acc[i][j] + bias[h0 + j], 0.f);
        float* dst = C + (size_t)(m0 + r0 + i) * 128 + h0;
        *reinterpret_cast<float4*>(dst)     = reinterpret_cast<float4&>(o[0]);
        *reinterpret_cast<float4*>(dst + 4) = reinterpret_cast<float4&>(o[4]);
    }
}

// ---------------------------------------------------------------------------
// final3: pool compacted wu rows (mean over n), two GEMVs, gates.
// ---------------------------------------------------------------------------
__global__ __launch_bounds__(1024) void final3_k(const int* __restrict__ wcnt,
                                                 const float* __restrict__ wuc,
                                                 const float* __restrict__ nh,
                                                 const float* __restrict__ wgW,
                                                 const float* __restrict__ wgb,
                                                 const float* __restrict__ fgW,
                                                 const float* __restrict__ fgb,
                                                 float* __restrict__ out) {
    const int b = blockIdx.x, t = threadIdx.x;
    const int d = t & 127, sl = t >> 7;
    __shared__ float red[1024];
    __shared__ float gw[Dn], nhs[Dn];
    const int n = wcnt[b];
    float acc = 0.f;
    for (int p = sl; p < n; p += 8) acc += wuc[((size_t)(b * 1024 + p)) * Dn + d];
    red[t] = acc;
    __syncthreads();
    for (int s = 512; s >= 128; s >>= 1) {
        if (t < s) red[t] += red[t + s];
        __syncthreads();
    }
    if (t < 128) {
        gw[t] = red[t] / ((float)n + 1e-30f);
        nhs[t] = nh[b * Dn + t];
    }
    __syncthreads();
    float pg = 0.f;
    for (int k = sl * 16; k < sl * 16 + 16; ++k) pg = fmaf(gw[k], wgW[k * Dn + d], pg);
    red[t] = pg;
    __syncthreads();
    for (int s = 512; s >= 128; s >>= 1) {
        if (t < s) red[t] += red[t + s];
        __syncthreads();
    }
    float gu = 0.f;
    if (t < 128) gu = fmaxf(red[t] + wgb[t], 0.f);
    __syncthreads();
    float pf = 0.f;
    for (int kk = sl * 32; kk < sl * 32 + 32; ++kk) {
        const float x = (kk < 128) ? gw[kk] : nhs[kk - 128];
        pf = fmaf(x, fgW[(size_t)kk * Dn + d], pf);
    }
    red[t] = pf;
    __syncthreads();
    for (int s = 512; s >= 128; s >>= 1) {
        if (t < s) red[t] += red[t + s];
        __syncthreads();
    }
    if (t < 128) {
        const float fg = red[t] + fgb[t];
        const float forget = 1.f / (1.f + expf(-fg));
        out[b * Dn + t] = fmaxf(forget, 0.1f) * nhs[t] + (1.f - forget) * gu;
    }
}

// ---------------------------------------------------------------------------
extern "C" void kernel_launch(void* const* d_in, const int* in_sizes, int n_in,
                              void* d_out, int out_size, void* d_ws, size_t ws_size,
                              hipStream_t stream) {
    (void)in_sizes; (void)n_in; (void)out_size; (void)ws_size;
    const float* word_outputs        = (const float*)d_in[0];
    const float* node_hidden         = (const float*)d_in[1];
    const float* op_embedding        = (const float*)d_in[2];
    const float* word_operator       = (const float*)d_in[3];
    const float* word_word           = (const float*)d_in[4];
    const float* depend_relation     = (const float*)d_in[5];
    const float* word_exist_matrix   = (const float*)d_in[6];
    const float* word_exist_sequence = (const float*)d_in[7];
    const float* goal_word           = (const float*)d_in[8];
    const float* o_w_W = (const float*)d_in[9];
    const float* o_w_b = (const float*)d_in[10];
    const float* wk_W  = (const float*)d_in[11];
    const float* wk_b  = (const float*)d_in[12];
    const float* ws_W  = (const float*)d_in[13];
    const float* ws_b  = (const float*)d_in[14];
    const float* up_W  = (const float*)d_in[15];
    const float* up_b  = (const float*)d_in[16];
    const float* wg_W  = (const float*)d_in[17];
    const float* wg_b  = (const float*)d_in[18];
    const float* fg_W  = (const float*)d_in[19];
    const float* fg_b  = (const float*)d_in[20];
    float* out = (float*)d_out;

    char* ws = (char*)d_ws;
    unsigned short* oph = (unsigned short*)(ws + 0);           // 128 KB
    unsigned short* wkh = (unsigned short*)(ws + (1u << 20));  // 4 MB
    unsigned short* wsh = (unsigned short*)(ws + (5u << 20));  // 4 MB
    int* widx           = (int*)(ws + (9u << 20));             // 32 KB
    int* wcnt           = (int*)(ws + (9u << 20) + 32768);     // 32 B
    unsigned short* nbc = (unsigned short*)(ws + (10u << 20)); // 8192*384*2 = 6 MB
    float* wuc          = (float*)(ws + (17u << 20));          // 8192*128*4 = 4 MB

    gemm_small<<<8, 256, 0, stream>>>(op_embedding, o_w_W, o_w_b, oph);
    gemm2_k<<<256, 256, 0, stream>>>(word_outputs, wk_W, ws_W, wk_b, ws_b, wkh, wsh);
    compact_k<<<8, 256, 0, stream>>>(goal_word, word_exist_sequence, widx, wcnt);
    mega_agg<<<8192, 256, 0, stream>>>(widx, wcnt, word_word, word_exist_matrix,
                                       depend_relation, word_operator, oph, wkh, wsh, nbc);
    up_gemm_c<<<128, 256, 0, stream>>>(nbc, up_W, up_b, wcnt, wuc);
    final3_k<<<8, 1024, 0, stream>>>(wcnt, wuc, node_hidden,
                                     wg_W, wg_b, fg_W, fg_b, out);
}